// Round 4
// baseline (4586.565 us; speedup 1.0000x reference)
//
#include <hip/hip_runtime.h>
#include <cmath>

// Problem: x (B,D,T) fp32, codebooks (L,K,D) fp32 -> out (B,D,T), indices (B,L,T)
constexpr int Bb = 32, Dd = 256, Tt = 2048, Ll = 8, Kk = 1024;
constexpr int VT = 64;            // vectors (rows) per block
constexpr int KT = 32;            // codes per k-tile
constexpr int ROWU = 264;         // padded row (ushorts)
constexpr int NTILE = Kk / KT;    // 32 tiles per layer
constexpr int TILE_STRIDE_USH = 8704;            // 32*264=8448 data + 256 pad -> 17408 B
constexpr int TILE_BYTES = TILE_STRIDE_USH * 2;  // 17408 B (= 17 x 1KB chunks)
constexpr int CHUNKS = TILE_BYTES / 1024;        // 17
constexpr int CSTR = 16;          // cand slots/row (cap; overflow -> exact full scan)

typedef __attribute__((ext_vector_type(8))) short short8;
typedef __attribute__((ext_vector_type(4))) float f32x4;

__device__ __forceinline__ ushort f2bf(float x) {
    union { float f; uint32_t u; } v{x};
    uint32_t r = v.u + 0x7fffu + ((v.u >> 16) & 1u);   // RNE
    return (ushort)(r >> 16);
}
__device__ __forceinline__ float bf2f(ushort h) {
    union { uint32_t u; float f; } v{((uint32_t)h) << 16};
    return v.f;
}
__device__ __forceinline__ void gl_lds16(const void* g, void* l) {
    __builtin_amdgcn_global_load_lds(
        (const __attribute__((address_space(1))) unsigned int*)g,
        (__attribute__((address_space(3))) unsigned int*)l, 16, 0, 0);
}
// distance key: index packed into mantissa low 10 bits (trunc err <= 1.2e-4 rel,
// absorbed by MARGIN); float ordering of keys == distance ordering within that err.
__device__ __forceinline__ float packkey(float d, int idx) {
    union { float f; uint32_t u; } v{d};
    v.u = (v.u & ~1023u) | (uint32_t)idx;
    return v.f;
}
__device__ __forceinline__ void top3_insert(float key, float& k1, float& k2, float& k3) {
    float t1 = fminf(k1, key), m1 = fmaxf(k1, key);
    float t2 = fminf(k2, m1),  m2 = fmaxf(k2, m1);
    k3 = fminf(k3, m2); k2 = t2; k1 = t1;
}

// ---------------------------------------------------------------------------
// Prep: wnorm (EXACT round-1 arithmetic: float4 expr + shfl_down tree) +
// bf16 HI-ONLY codebook in padded KT=32 tile-blocked layout (global layout ==
// LDS layout so global_load_lds stages each tile as a flat byte copy).
__global__ void prep_kernel(const float* __restrict__ cb, float* __restrict__ wn,
                            ushort* __restrict__ sp) {
    const int code = blockIdx.x;          // 0 .. L*K-1
    const int lane = threadIdx.x;         // 0 .. 63
    const int l = code >> 10, kk = code & 1023, kt = kk >> 5, kr = kk & 31;
    const float4 v = ((const float4*)(cb + (size_t)code * Dd))[lane];
    float s = v.x * v.x + v.y * v.y + v.z * v.z + v.w * v.w;
#pragma unroll
    for (int off = 32; off > 0; off >>= 1) s += __shfl_down(s, off, 64);
    if (lane == 0) wn[code] = s;

    float f[4] = {v.x, v.y, v.z, v.w};
    ushort hs[4];
#pragma unroll
    for (int i = 0; i < 4; ++i) hs[i] = f2bf(f[i]);
    ushort* base = sp + (size_t)(l * NTILE + kt) * TILE_STRIDE_USH + kr * ROWU + lane * 4;
    *(ushort4*)base = make_ushort4(hs[0], hs[1], hs[2], hs[3]);
}

// ---------------------------------------------------------------------------
// Residual held as EXACT bf16 triple (hi+mid+lo == fp32 value, Dekker split:
// 24 mantissa bits = 3x8). Filter MFMAs use (hi, mid) == R1's (ah, al).
// Rescore recomputes the exact residual from x + index history (identical
// elementwise subtraction order -> bit-identical), so no fp32 LDS copy needed.
__launch_bounds__(256, 3)
__global__ void rvq_kernel(const float* __restrict__ x, const float* __restrict__ cb,
                           const float* __restrict__ wn, const ushort* __restrict__ sp,
                           float* __restrict__ out, float* __restrict__ oidx) {
    __shared__ __align__(16) ushort Btile[2 * TILE_STRIDE_USH];  // 34816 B dbuf
    __shared__ int cnt[VT];
    __shared__ int cand[VT * CSTR];
    __shared__ int hist[Ll][VT];

    const int tid = threadIdx.x;
    const int w = tid >> 6, lane = tid & 63;
    const int c = lane & 15;          // MFMA: A row m / B col n
    const int q = lane >> 4;          // quad
    const int b = blockIdx.x >> 5, t0 = (blockIdx.x & 31) * VT;
    const int myrow = 16 * w + c;     // residual row owned by this lane (A layout)
    const int t_a = t0 + myrow;

    // load x, triple-split: A-fragment layout elem = r[myrow][32s+8q+j]
    short8 Ah[8], Am[8], Al[8];
    {
        const float* xb = x + (size_t)b * Dd * Tt + t_a;
#pragma unroll
        for (int s = 0; s < 8; ++s)
#pragma unroll
            for (int j = 0; j < 8; ++j) {
                float v = xb[(size_t)(32 * s + 8 * q + j) * Tt];
                ushort h_ = f2bf(v); float r1 = v - bf2f(h_);
                ushort m_ = f2bf(r1); float r2 = r1 - bf2f(m_);
                Ah[s][j] = (short)h_; Am[s][j] = (short)m_; Al[s][j] = (short)f2bf(r2);
            }
    }

    for (int ly = 0; ly < Ll; ++ly) {
        const float*  cbl = cb + (size_t)ly * Kk * Dd;
        const float*  wnl = wn + ly * Kk;
        const ushort* spl = sp + (size_t)ly * NTILE * TILE_STRIDE_USH;

        float k1[4], k2[4], k3[4];
#pragma unroll
        for (int i = 0; i < 4; ++i) { k1[i] = __builtin_inff(); k2[i] = __builtin_inff(); k3[i] = __builtin_inff(); }

        auto STAGE = [&](int kt2, int buf) {
            const char* gsrc = (const char*)spl + (size_t)kt2 * TILE_BYTES;
            char* ldst = (char*)Btile + buf * TILE_BYTES;
            for (int ch = w; ch < CHUNKS; ch += 4)
                gl_lds16(gsrc + ch * 1024 + lane * 16, ldst + ch * 1024);
        };

        STAGE(0, 0);
        for (int kt = 0; kt < NTILE; ++kt) {
            // single barrier/tile: drains this tile's staging (issued last iter,
            // overlapped with previous compute) and orders buffer reuse.
            __syncthreads();
            if (kt < NTILE - 1) STAGE(kt + 1, (kt + 1) & 1);

            const ushort* bt = Btile + (kt & 1) * TILE_STRIDE_USH;
            float wnv0 = wnl[kt * KT + c];
            float wnv1 = wnl[kt * KT + 16 + c];

            f32x4 a0h = (f32x4)0.f, a1h = (f32x4)0.f, a0m = (f32x4)0.f, a1m = (f32x4)0.f;
#pragma unroll
            for (int s = 0; s < 8; ++s) {
                const ushort* bp = bt + s * 32 + q * 8;
                short8 b0 = *(const short8*)(bp + c * ROWU);
                short8 b1 = *(const short8*)(bp + (16 + c) * ROWU);
                a0h = __builtin_amdgcn_mfma_f32_16x16x32_bf16(Ah[s], b0, a0h, 0, 0, 0);
                a1h = __builtin_amdgcn_mfma_f32_16x16x32_bf16(Ah[s], b1, a1h, 0, 0, 0);
                a0m = __builtin_amdgcn_mfma_f32_16x16x32_bf16(Am[s], b0, a0m, 0, 0, 0);
                a1m = __builtin_amdgcn_mfma_f32_16x16x32_bf16(Am[s], b1, a1m, 0, 0, 0);
            }
#pragma unroll
            for (int i = 0; i < 4; ++i) {
                float dA = fmaf(-2.f, a0h[i] + a0m[i], wnv0);   // (hi+mid).b_hi rel dist
                top3_insert(packkey(dA, kt * KT + c),      k1[i], k2[i], k3[i]);
                float dB = fmaf(-2.f, a1h[i] + a1m[i], wnv1);
                top3_insert(packkey(dB, kt * KT + 16 + c), k1[i], k2[i], k3[i]);
            }
        }

        if (tid < VT) cnt[tid] = 0;   // cnt untouched in k-loop; barrier below orders

        // per-row approx min across the 16 c-lanes (same q) owning the row
        float bmin[4];
#pragma unroll
        for (int i = 0; i < 4; ++i) {
            float md = k1[i];
#pragma unroll
            for (int off = 1; off < 16; off <<= 1)
                md = fminf(md, __shfl_xor(md, off, 64));
            bmin[i] = md;
        }
        __syncthreads();  // cnt zeroed visible

        // margin filter -> candidate lists. MARGIN=1.5 covers hi-only filter
        // error (~6sigma each side) + key truncation (<=0.05).
#pragma unroll
        for (int i = 0; i < 4; ++i) {
            const int row = 16 * w + 4 * q + i;
            const float thr = bmin[i] + 1.5f;
            if (k1[i] <= thr) { union { float f; uint32_t u; } v{k1[i]}; int pos = atomicAdd(&cnt[row], 1); if (pos < CSTR) cand[row * CSTR + pos] = (int)(v.u & 1023u); }
            if (k2[i] <= thr) { union { float f; uint32_t u; } v{k2[i]}; int pos = atomicAdd(&cnt[row], 1); if (pos < CSTR) cand[row * CSTR + pos] = (int)(v.u & 1023u); }
            if (k3[i] <= thr) { union { float f; uint32_t u; } v{k3[i]}; int pos = atomicAdd(&cnt[row], 1); if (pos < CSTR) cand[row * CSTR + pos] = (int)(v.u & 1023u); }
        }
        __syncthreads();

        // Final selection, spread across all 4 waves (1 row per lane-quad).
        // cnt==1: candidate IS the argmin. cnt>1: recompute exact residual
        // from x + hist (bit-identical: same elementwise subtract order) and
        // rescore with BIT-EXACT round-1 arithmetic (sequential ascending fmaf
        // dot, float4 rnorm expression order, identical wnorm & dist expr).
        if ((tid & 3) == 0) {
            const int row = tid >> 2;
            const int n = cnt[row];
            int bi = cand[row * CSTR];
            if (n > 1) {
                __align__(16) float rr[256];
                const float* xr = x + (size_t)b * Dd * Tt + (t0 + row);
                for (int d = 0; d < Dd; ++d) rr[d] = xr[(size_t)d * Tt];
                for (int l2 = 0; l2 < ly; ++l2) {
                    const float* wp = cb + ((size_t)l2 * Kk + hist[l2][row]) * Dd;
                    for (int d = 0; d < Dd; ++d) rr[d] -= wp[d];
                }
                float rn = 0.f;
                for (int i2 = 0; i2 < Dd / 4; ++i2) {
                    float4 r4 = *(const float4*)(rr + 4 * i2);
                    rn += r4.x * r4.x + r4.y * r4.y + r4.z * r4.z + r4.w * r4.w;
                }
                const bool ovf = n > CSTR;       // cand list overflowed: exact scan
                const int m = ovf ? Kk : n;
                float bd = __builtin_inff(); bi = 0x7fffffff;
                for (int j = 0; j < m; ++j) {
                    const int cc = ovf ? j : cand[row * CSTR + j];
                    const float* wp = cbl + (size_t)cc * Dd;
                    float dot = 0.f;
                    for (int d = 0; d < Dd; ++d)
                        dot = fmaf(rr[d], wp[d], dot);
                    const float dist = (rn - 2.0f * dot) + wnl[cc];
                    if (dist < bd || (dist == bd && cc < bi)) { bd = dist; bi = cc; }
                }
            }
            hist[ly][row] = bi;
            oidx[((size_t)b * Ll + ly) * Tt + t0 + row] = (float)bi;
        }
        __syncthreads();

        // residual update: reconstruct exact fp32 (hi+mid)+lo, subtract chosen
        // code (original fp32 codebook), re-split. Bit-identical to R1's chain.
        {
            const int cc = hist[ly][myrow];
            const float* wp = cbl + (size_t)cc * Dd + 8 * q;
#pragma unroll
            for (int s = 0; s < 8; ++s) {
                float4 w0 = *(const float4*)(wp + 32 * s);
                float4 w1 = *(const float4*)(wp + 32 * s + 4);
                float wv[8] = {w0.x, w0.y, w0.z, w0.w, w1.x, w1.y, w1.z, w1.w};
#pragma unroll
                for (int j = 0; j < 8; ++j) {
                    float Rv = (bf2f((ushort)Ah[s][j]) + bf2f((ushort)Am[s][j])) + bf2f((ushort)Al[s][j]);
                    Rv -= wv[j];
                    ushort h_ = f2bf(Rv); float r1 = Rv - bf2f(h_);
                    ushort m_ = f2bf(r1); float r2 = r1 - bf2f(m_);
                    Ah[s][j] = (short)h_; Am[s][j] = (short)m_; Al[s][j] = (short)f2bf(r2);
                }
            }
        }
    }

    // out = x - final residual (exact reconstruct)
    {
        const float* xb = x + (size_t)b * Dd * Tt + t_a;
        float* ob = out + (size_t)b * Dd * Tt + t_a;
#pragma unroll
        for (int s = 0; s < 8; ++s)
#pragma unroll
            for (int j = 0; j < 8; ++j) {
                size_t off = (size_t)(32 * s + 8 * q + j) * Tt;
                float Rv = (bf2f((ushort)Ah[s][j]) + bf2f((ushort)Am[s][j])) + bf2f((ushort)Al[s][j]);
                ob[off] = xb[off] - Rv;
            }
    }
}

// ---------------------------------------------------------------------------
extern "C" void kernel_launch(void* const* d_in, const int* in_sizes, int n_in,
                              void* d_out, int out_size, void* d_ws, size_t ws_size,
                              hipStream_t stream) {
    const float* x  = (const float*)d_in[0];   // (B, D, T)
    const float* cb = (const float*)d_in[1];   // (L, K, D)
    float* out  = (float*)d_out;
    float* oidx = out + (size_t)Bb * Dd * Tt;  // (B, L, T) as fp32 values
    float*  wnbuf = (float*)d_ws;                          // 8192 floats
    ushort* spbuf = (ushort*)((char*)d_ws + 32768);        // hi-split codebook, ~4.46 MB

    prep_kernel<<<Ll * Kk, 64, 0, stream>>>(cb, wnbuf, spbuf);
    rvq_kernel<<<(Bb * Tt) / VT, 256, 0, stream>>>(x, cb, wnbuf, spbuf, out, oidx);
}

// Round 5
// 1877.153 us; speedup vs baseline: 2.4434x; 2.4434x over previous
//
#include <hip/hip_runtime.h>
#include <cmath>

// Problem: x (B,D,T) fp32, codebooks (L,K,D) fp32 -> out (B,D,T), indices (B,L,T)
constexpr int Bb = 32, Dd = 256, Tt = 2048, Ll = 8, Kk = 1024;
constexpr int VT = 64;            // vectors (rows) per block
constexpr int KT = 32;            // codes per k-tile
constexpr int ROWU = 264;         // padded row (ushorts)
constexpr int NTILE = Kk / KT;    // 32 tiles per layer
constexpr int TILE_STRIDE_USH = 8704;            // 32*264=8448 data + 256 pad -> 17408 B
constexpr int TILE_BYTES = TILE_STRIDE_USH * 2;  // 17408 B (= 17 x 1KB chunks)
constexpr int CHUNKS = TILE_BYTES / 1024;        // 17
constexpr int CSTR = 16;          // cand slots/row (cap; overflow -> exact full scan)
constexpr int RSTR = 258;         // rescore scratch stride (floats): float2-aligned, <=2-way banks
constexpr int RBATCH = 32;        // rescore rows per batch (32*258*4 = 33024 B <= 34816 B)

typedef __attribute__((ext_vector_type(8))) short short8;
typedef __attribute__((ext_vector_type(4))) float f32x4;

__device__ __forceinline__ ushort f2bf(float x) {
    union { float f; uint32_t u; } v{x};
    uint32_t r = v.u + 0x7fffu + ((v.u >> 16) & 1u);   // RNE
    return (ushort)(r >> 16);
}
__device__ __forceinline__ float bf2f(ushort h) {
    union { uint32_t u; float f; } v{((uint32_t)h) << 16};
    return v.f;
}
__device__ __forceinline__ void gl_lds16(const void* g, void* l) {
    __builtin_amdgcn_global_load_lds(
        (const __attribute__((address_space(1))) unsigned int*)g,
        (__attribute__((address_space(3))) unsigned int*)l, 16, 0, 0);
}
// distance key: index packed into mantissa low 10 bits (trunc err <= ~1.2e-4 rel,
// absorbed by MARGIN); float ordering of keys == distance ordering within that err.
__device__ __forceinline__ float packkey(float d, int idx) {
    union { float f; uint32_t u; } v{d};
    v.u = (v.u & ~1023u) | (uint32_t)idx;
    return v.f;
}
__device__ __forceinline__ void top3_insert(float key, float& k1, float& k2, float& k3) {
    float t1 = fminf(k1, key), m1 = fmaxf(k1, key);
    float t2 = fminf(k2, m1),  m2 = fmaxf(k2, m1);
    k3 = fminf(k3, m2); k2 = t2; k1 = t1;
}

// ---------------------------------------------------------------------------
// Prep: wnorm (EXACT round-1 arithmetic: float4 expr + shfl_down tree) +
// bf16 HI-ONLY codebook in padded KT=32 tile-blocked layout (global layout ==
// LDS layout so global_load_lds stages each tile as a flat byte copy).
__global__ void prep_kernel(const float* __restrict__ cb, float* __restrict__ wn,
                            ushort* __restrict__ sp) {
    const int code = blockIdx.x;          // 0 .. L*K-1
    const int lane = threadIdx.x;         // 0 .. 63
    const int l = code >> 10, kk = code & 1023, kt = kk >> 5, kr = kk & 31;
    const float4 v = ((const float4*)(cb + (size_t)code * Dd))[lane];
    float s = v.x * v.x + v.y * v.y + v.z * v.z + v.w * v.w;
#pragma unroll
    for (int off = 32; off > 0; off >>= 1) s += __shfl_down(s, off, 64);
    if (lane == 0) wn[code] = s;

    float f[4] = {v.x, v.y, v.z, v.w};
    ushort hs[4];
#pragma unroll
    for (int i = 0; i < 4; ++i) hs[i] = f2bf(f[i]);
    ushort* base = sp + (size_t)(l * NTILE + kt) * TILE_STRIDE_USH + kr * ROWU + lane * 4;
    *(ushort4*)base = make_ushort4(hs[0], hs[1], hs[2], hs[3]);
}

// ---------------------------------------------------------------------------
// Residual held as EXACT bf16 triple (hi+mid+lo == fp32 value, Dekker split:
// 24 mantissa bits = 3x8). Filter MFMAs use (hi, mid). Rescore: rows needing
// it dump their exact fp32 residual (reconstructed from the triple) into the
// dead Btile space after the k-loop -- no per-thread scratch arrays anywhere.
__launch_bounds__(256, 3)
__global__ void rvq_kernel(const float* __restrict__ x, const float* __restrict__ cb,
                           const float* __restrict__ wn, const ushort* __restrict__ sp,
                           float* __restrict__ out, float* __restrict__ oidx) {
    __shared__ __align__(16) ushort Btile[2 * TILE_STRIDE_USH];  // 34816 B dbuf / rescore scratch
    __shared__ int sidx[VT];
    __shared__ int cnt[VT];
    __shared__ int slot[VT];
    __shared__ int cand[VT * CSTR];
    __shared__ int nresc;

    const int tid = threadIdx.x;
    const int w = tid >> 6, lane = tid & 63;
    const int c = lane & 15;          // MFMA: A row m / B col n
    const int q = lane >> 4;          // quad
    const int b = blockIdx.x >> 5, t0 = (blockIdx.x & 31) * VT;
    const int myrow = 16 * w + c;     // residual row owned by this lane (A layout)
    const int t_a = t0 + myrow;

    // load x, triple-split: A-fragment layout elem = r[myrow][32s+8q+j]
    short8 Ah[8], Am[8], Al[8];
    {
        const float* xb = x + (size_t)b * Dd * Tt + t_a;
#pragma unroll
        for (int s = 0; s < 8; ++s)
#pragma unroll
            for (int j = 0; j < 8; ++j) {
                float v = xb[(size_t)(32 * s + 8 * q + j) * Tt];
                ushort h_ = f2bf(v); float r1 = v - bf2f(h_);
                ushort m_ = f2bf(r1); float r2 = r1 - bf2f(m_);
                Ah[s][j] = (short)h_; Am[s][j] = (short)m_; Al[s][j] = (short)f2bf(r2);
            }
    }

    for (int ly = 0; ly < Ll; ++ly) {
        const float*  cbl = cb + (size_t)ly * Kk * Dd;
        const float*  wnl = wn + ly * Kk;
        const ushort* spl = sp + (size_t)ly * NTILE * TILE_STRIDE_USH;

        float k1[4], k2[4], k3[4];
#pragma unroll
        for (int i = 0; i < 4; ++i) { k1[i] = __builtin_inff(); k2[i] = __builtin_inff(); k3[i] = __builtin_inff(); }

        auto STAGE = [&](int kt2, int buf) {
            const char* gsrc = (const char*)spl + (size_t)kt2 * TILE_BYTES;
            char* ldst = (char*)Btile + buf * TILE_BYTES;
            for (int ch = w; ch < CHUNKS; ch += 4)
                gl_lds16(gsrc + ch * 1024 + lane * 16, ldst + ch * 1024);
        };

        STAGE(0, 0);
        for (int kt = 0; kt < NTILE; ++kt) {
            // single barrier/tile: drains this tile's staging (issued last iter,
            // overlapped with previous compute) and orders buffer reuse.
            __syncthreads();
            if (kt < NTILE - 1) STAGE(kt + 1, (kt + 1) & 1);

            const ushort* bt = Btile + (kt & 1) * TILE_STRIDE_USH;
            float wnv0 = wnl[kt * KT + c];
            float wnv1 = wnl[kt * KT + 16 + c];

            f32x4 a0h = (f32x4)0.f, a1h = (f32x4)0.f, a0m = (f32x4)0.f, a1m = (f32x4)0.f;
#pragma unroll
            for (int s = 0; s < 8; ++s) {
                const ushort* bp = bt + s * 32 + q * 8;
                short8 b0 = *(const short8*)(bp + c * ROWU);
                short8 b1 = *(const short8*)(bp + (16 + c) * ROWU);
                a0h = __builtin_amdgcn_mfma_f32_16x16x32_bf16(Ah[s], b0, a0h, 0, 0, 0);
                a1h = __builtin_amdgcn_mfma_f32_16x16x32_bf16(Ah[s], b1, a1h, 0, 0, 0);
                a0m = __builtin_amdgcn_mfma_f32_16x16x32_bf16(Am[s], b0, a0m, 0, 0, 0);
                a1m = __builtin_amdgcn_mfma_f32_16x16x32_bf16(Am[s], b1, a1m, 0, 0, 0);
            }
#pragma unroll
            for (int i = 0; i < 4; ++i) {
                float dA = fmaf(-2.f, a0h[i] + a0m[i], wnv0);   // (hi+mid).b_hi rel dist
                top3_insert(packkey(dA, kt * KT + c),      k1[i], k2[i], k3[i]);
                float dB = fmaf(-2.f, a1h[i] + a1m[i], wnv1);
                top3_insert(packkey(dB, kt * KT + 16 + c), k1[i], k2[i], k3[i]);
            }
        }

        if (tid < VT) cnt[tid] = 0;   // cnt untouched in k-loop; barrier below orders
        if (tid == 0) nresc = 0;

        // per-row approx min across the 16 c-lanes (same q) owning the row
        float bmin[4];
#pragma unroll
        for (int i = 0; i < 4; ++i) {
            float md = k1[i];
#pragma unroll
            for (int off = 1; off < 16; off <<= 1)
                md = fminf(md, __shfl_xor(md, off, 64));
            bmin[i] = md;
        }
        __syncthreads();  // (A) cnt/nresc zero visible; all Btile ds_reads done

        // margin filter -> candidate lists. MARGIN=1.25 covers hi-only filter
        // error (sigma<=~0.09, R1-proven at 1.0) + packed-key truncation (<=~0.1).
#pragma unroll
        for (int i = 0; i < 4; ++i) {
            const int row = 16 * w + 4 * q + i;
            const float thr = bmin[i] + 1.25f;
            if (k1[i] <= thr) { union { float f; uint32_t u; } v{k1[i]}; int pos = atomicAdd(&cnt[row], 1); if (pos < CSTR) cand[row * CSTR + pos] = (int)(v.u & 1023u); }
            if (k2[i] <= thr) { union { float f; uint32_t u; } v{k2[i]}; int pos = atomicAdd(&cnt[row], 1); if (pos < CSTR) cand[row * CSTR + pos] = (int)(v.u & 1023u); }
            if (k3[i] <= thr) { union { float f; uint32_t u; } v{k3[i]}; int pos = atomicAdd(&cnt[row], 1); if (pos < CSTR) cand[row * CSTR + pos] = (int)(v.u & 1023u); }
        }
        __syncthreads();  // (B) cand/cnt final

        // compact worklist of rows needing exact rescore (cnt>1, incl. overflow)
        if (tid < VT) slot[tid] = (cnt[tid] > 1) ? atomicAdd(&nresc, 1) : -1;
        __syncthreads();  // (C) slots + nresc known
        const int nr = nresc;

        // fast path: unique candidate IS the argmin
        if (tid < VT && cnt[tid] <= 1) {
            const int bi = cand[tid * CSTR];
            sidx[tid] = bi;
            oidx[((size_t)b * Ll + ly) * Tt + t0 + tid] = (float)bi;
        }

        // rescore batches: Btile is dead -> scratch of RBATCH exact fp32 rows.
        float* Rsc = (float*)Btile;
        for (int base = 0; base < nr; base += RBATCH) {
            // dump: each of the row's 4 owning lanes writes its 64 elems (exact
            // (hi+mid)+lo reconstruction == the fp32 residual, bit-identical)
            {
                const int sl = slot[myrow];
                if (sl >= base && sl < base + RBATCH) {
                    float* dst = Rsc + (size_t)(sl - base) * RSTR + 8 * q;
#pragma unroll
                    for (int s = 0; s < 8; ++s)
#pragma unroll
                        for (int jp = 0; jp < 4; ++jp) {
                            float e0 = (bf2f((ushort)Ah[s][2 * jp]) + bf2f((ushort)Am[s][2 * jp])) + bf2f((ushort)Al[s][2 * jp]);
                            float e1 = (bf2f((ushort)Ah[s][2 * jp + 1]) + bf2f((ushort)Am[s][2 * jp + 1])) + bf2f((ushort)Al[s][2 * jp + 1]);
                            *(float2*)(dst + 32 * s + 2 * jp) = make_float2(e0, e1);
                        }
                }
            }
            __syncthreads();  // dump visible

            // rescore with BIT-EXACT round-1 arithmetic (sequential ascending
            // fmaf dot, groups-of-4 rnorm expression, identical wnorm & dist
            // expr, cc<bi tie-break) so the chosen index replicates the
            // proven-passing kernel.
            if (tid < VT) {
                const int sl = slot[tid];
                if (sl >= base && sl < base + RBATCH) {
                    const int row = tid;
                    const int n = cnt[row];
                    const float* rp = Rsc + (size_t)(sl - base) * RSTR;
                    float rn = 0.f;
                    for (int i2 = 0; i2 < Dd / 4; ++i2) {
                        float r0 = rp[4 * i2], r1 = rp[4 * i2 + 1], r2 = rp[4 * i2 + 2], r3 = rp[4 * i2 + 3];
                        rn += r0 * r0 + r1 * r1 + r2 * r2 + r3 * r3;
                    }
                    const bool ovf = n > CSTR;       // cand list overflowed: exact full scan
                    const int m = ovf ? Kk : n;
                    float bd = __builtin_inff(); int bi = 0x7fffffff;
                    for (int j = 0; j < m; ++j) {
                        const int cc = ovf ? j : cand[row * CSTR + j];
                        const float* wp = cbl + (size_t)cc * Dd;
                        float dot = 0.f;
                        for (int d = 0; d < Dd; ++d)
                            dot = fmaf(rp[d], wp[d], dot);
                        const float dist = (rn - 2.0f * dot) + wnl[cc];
                        if (dist < bd || (dist == bd && cc < bi)) { bd = dist; bi = cc; }
                    }
                    sidx[row] = bi;
                    oidx[((size_t)b * Ll + ly) * Tt + t0 + row] = (float)bi;
                }
            }
            __syncthreads();  // rescore reads done before next batch's dump
        }
        __syncthreads();  // (E) sidx complete (fast path + all batches)

        // residual update: reconstruct exact fp32 (hi+mid)+lo, subtract chosen
        // code (original fp32 codebook), re-split. Exact chain.
        {
            const int cc = sidx[myrow];
            const float* wp = cbl + (size_t)cc * Dd + 8 * q;
#pragma unroll
            for (int s = 0; s < 8; ++s) {
                float4 w0 = *(const float4*)(wp + 32 * s);
                float4 w1 = *(const float4*)(wp + 32 * s + 4);
                float wv[8] = {w0.x, w0.y, w0.z, w0.w, w1.x, w1.y, w1.z, w1.w};
#pragma unroll
                for (int j = 0; j < 8; ++j) {
                    float Rv = (bf2f((ushort)Ah[s][j]) + bf2f((ushort)Am[s][j])) + bf2f((ushort)Al[s][j]);
                    Rv -= wv[j];
                    ushort h_ = f2bf(Rv); float r1 = Rv - bf2f(h_);
                    ushort m_ = f2bf(r1); float r2 = r1 - bf2f(m_);
                    Ah[s][j] = (short)h_; Am[s][j] = (short)m_; Al[s][j] = (short)f2bf(r2);
                }
            }
        }
    }

    // out = x - final residual (exact reconstruct)
    {
        const float* xb = x + (size_t)b * Dd * Tt + t_a;
        float* ob = out + (size_t)b * Dd * Tt + t_a;
#pragma unroll
        for (int s = 0; s < 8; ++s)
#pragma unroll
            for (int j = 0; j < 8; ++j) {
                size_t off = (size_t)(32 * s + 8 * q + j) * Tt;
                float Rv = (bf2f((ushort)Ah[s][j]) + bf2f((ushort)Am[s][j])) + bf2f((ushort)Al[s][j]);
                ob[off] = xb[off] - Rv;
            }
    }
}

// ---------------------------------------------------------------------------
extern "C" void kernel_launch(void* const* d_in, const int* in_sizes, int n_in,
                              void* d_out, int out_size, void* d_ws, size_t ws_size,
                              hipStream_t stream) {
    const float* x  = (const float*)d_in[0];   // (B, D, T)
    const float* cb = (const float*)d_in[1];   // (L, K, D)
    float* out  = (float*)d_out;
    float* oidx = out + (size_t)Bb * Dd * Tt;  // (B, L, T) as fp32 values
    float*  wnbuf = (float*)d_ws;                          // 8192 floats
    ushort* spbuf = (ushort*)((char*)d_ws + 32768);        // hi-split codebook, ~4.46 MB

    prep_kernel<<<Ll * Kk, 64, 0, stream>>>(cb, wnbuf, spbuf);
    rvq_kernel<<<(Bb * Tt) / VT, 256, 0, stream>>>(x, cb, wnbuf, spbuf, out, oidx);
}

// Round 6
// 1276.522 us; speedup vs baseline: 3.5930x; 1.4705x over previous
//
#include <hip/hip_runtime.h>
#include <cmath>

// Problem: x (B,D,T) fp32, codebooks (L,K,D) fp32 -> out (B,D,T), indices (B,L,T)
constexpr int Bb = 32, Dd = 256, Tt = 2048, Ll = 8, Kk = 1024;
constexpr int VT = 64;            // vectors (rows) per block
constexpr int KT = 32;            // codes per k-tile
constexpr int ROWU = 264;         // padded row (ushorts)
constexpr int NTILE = Kk / KT;    // 32 tiles per layer
constexpr int TILE_STRIDE_USH = 8704;            // 32*264=8448 data + 256 pad -> 17408 B
constexpr int TILE_BYTES = TILE_STRIDE_USH * 2;  // 17408 B (= 17 x 1KB chunks)
constexpr int CHUNKS = TILE_BYTES / 1024;        // 17
constexpr int CSTR = 16;          // cand slots/row (cap; overflow -> exact full scan)
constexpr int RSTR = 258;         // rescore scratch stride (floats): float2-aligned, <=2-way banks
constexpr int RBATCH = 32;        // rescore rows per batch (32*258*4 = 33024 B <= 34816 B)

typedef __attribute__((ext_vector_type(8))) short short8;
typedef __attribute__((ext_vector_type(4))) float f32x4;

__device__ __forceinline__ ushort f2bf(float x) {
    union { float f; uint32_t u; } v{x};
    uint32_t r = v.u + 0x7fffu + ((v.u >> 16) & 1u);   // RNE
    return (ushort)(r >> 16);
}
__device__ __forceinline__ float bf2f(ushort h) {
    union { uint32_t u; float f; } v{((uint32_t)h) << 16};
    return v.f;
}
__device__ __forceinline__ void gl_lds16(const void* g, void* l) {
    __builtin_amdgcn_global_load_lds(
        (const __attribute__((address_space(1))) unsigned int*)g,
        (__attribute__((address_space(3))) unsigned int*)l, 16, 0, 0);
}
// distance key: index packed into mantissa low 10 bits (trunc err <= ~1.2e-4 rel,
// absorbed by MARGIN); float ordering of keys == distance ordering within that err.
__device__ __forceinline__ float packkey(float d, int idx) {
    union { float f; uint32_t u; } v{d};
    v.u = (v.u & ~1023u) | (uint32_t)idx;
    return v.f;
}
__device__ __forceinline__ void top3_insert(float key, float& k1, float& k2, float& k3) {
    float t1 = fminf(k1, key), m1 = fmaxf(k1, key);
    float t2 = fminf(k2, m1),  m2 = fmaxf(k2, m1);
    k3 = fminf(k3, m2); k2 = t2; k1 = t1;
}

// ---------------------------------------------------------------------------
// Prep: wnorm (EXACT round-1 arithmetic: float4 expr + shfl_down tree) +
// bf16 HI-ONLY codebook in padded KT=32 tile-blocked layout (global layout ==
// LDS layout so global_load_lds stages each tile as a flat byte copy).
__global__ void prep_kernel(const float* __restrict__ cb, float* __restrict__ wn,
                            ushort* __restrict__ sp) {
    const int code = blockIdx.x;          // 0 .. L*K-1
    const int lane = threadIdx.x;         // 0 .. 63
    const int l = code >> 10, kk = code & 1023, kt = kk >> 5, kr = kk & 31;
    const float4 v = ((const float4*)(cb + (size_t)code * Dd))[lane];
    float s = v.x * v.x + v.y * v.y + v.z * v.z + v.w * v.w;
#pragma unroll
    for (int off = 32; off > 0; off >>= 1) s += __shfl_down(s, off, 64);
    if (lane == 0) wn[code] = s;

    float f[4] = {v.x, v.y, v.z, v.w};
    ushort hs[4];
#pragma unroll
    for (int i = 0; i < 4; ++i) hs[i] = f2bf(f[i]);
    ushort* base = sp + (size_t)(l * NTILE + kt) * TILE_STRIDE_USH + kr * ROWU + lane * 4;
    *(ushort4*)base = make_ushort4(hs[0], hs[1], hs[2], hs[3]);
}

// ---------------------------------------------------------------------------
// Residual held as EXACT bf16 triple (hi+mid+lo == fp32 value, Dekker split:
// 24 mantissa bits = 3x8). Filter MFMAs use (hi, mid). Rescore: rows needing
// it dump their exact fp32 residual (reconstructed from the triple) into the
// dead Btile space after the k-loop -- no per-thread scratch arrays anywhere.
// __launch_bounds__(256,2): with MFMA present the allocator splits the
// per-SIMD budget (512/min_waves) evenly arch/AGPR -> arch budget 128.
// (256,3) gave 84 arch -> forced k-loop spills (R4/R5, 1.6+ GB scratch).
// Actual occupancy: ~128 arch + ~16 agpr ~= 144/wave -> 3 waves/SIMD,
// LDS 39936 B -> 3 blocks/CU co-resident.
__launch_bounds__(256, 2)
__global__ void rvq_kernel(const float* __restrict__ x, const float* __restrict__ cb,
                           const float* __restrict__ wn, const ushort* __restrict__ sp,
                           float* __restrict__ out, float* __restrict__ oidx) {
    __shared__ __align__(16) ushort Btile[2 * TILE_STRIDE_USH];  // 34816 B dbuf / rescore scratch
    __shared__ int sidx[VT];
    __shared__ int cnt[VT];
    __shared__ int slot[VT];
    __shared__ int cand[VT * CSTR];
    __shared__ int nresc;

    const int tid = threadIdx.x;
    const int w = tid >> 6, lane = tid & 63;
    const int c = lane & 15;          // MFMA: A row m / B col n
    const int q = lane >> 4;          // quad
    const int b = blockIdx.x >> 5, t0 = (blockIdx.x & 31) * VT;
    const int myrow = 16 * w + c;     // residual row owned by this lane (A layout)
    const int t_a = t0 + myrow;

    // load x, triple-split: A-fragment layout elem = r[myrow][32s+8q+j]
    short8 Ah[8], Am[8], Al[8];
    {
        const float* xb = x + (size_t)b * Dd * Tt + t_a;
#pragma unroll
        for (int s = 0; s < 8; ++s)
#pragma unroll
            for (int j = 0; j < 8; ++j) {
                float v = xb[(size_t)(32 * s + 8 * q + j) * Tt];
                ushort h_ = f2bf(v); float r1 = v - bf2f(h_);
                ushort m_ = f2bf(r1); float r2 = r1 - bf2f(m_);
                Ah[s][j] = (short)h_; Am[s][j] = (short)m_; Al[s][j] = (short)f2bf(r2);
            }
    }

    for (int ly = 0; ly < Ll; ++ly) {
        const float*  cbl = cb + (size_t)ly * Kk * Dd;
        const float*  wnl = wn + ly * Kk;
        const ushort* spl = sp + (size_t)ly * NTILE * TILE_STRIDE_USH;

        float k1[4], k2[4], k3[4];
#pragma unroll
        for (int i = 0; i < 4; ++i) { k1[i] = __builtin_inff(); k2[i] = __builtin_inff(); k3[i] = __builtin_inff(); }

        auto STAGE = [&](int kt2, int buf) {
            const char* gsrc = (const char*)spl + (size_t)kt2 * TILE_BYTES;
            char* ldst = (char*)Btile + buf * TILE_BYTES;
            for (int ch = w; ch < CHUNKS; ch += 4)
                gl_lds16(gsrc + ch * 1024 + lane * 16, ldst + ch * 1024);
        };

        STAGE(0, 0);
        for (int kt = 0; kt < NTILE; ++kt) {
            // single barrier/tile: drains this tile's staging (issued last iter,
            // overlapped with previous compute) and orders buffer reuse.
            __syncthreads();
            if (kt < NTILE - 1) STAGE(kt + 1, (kt + 1) & 1);

            const ushort* bt = Btile + (kt & 1) * TILE_STRIDE_USH;
            float wnv0 = wnl[kt * KT + c];
            float wnv1 = wnl[kt * KT + 16 + c];

            f32x4 a0h = (f32x4)0.f, a1h = (f32x4)0.f, a0m = (f32x4)0.f, a1m = (f32x4)0.f;
#pragma unroll
            for (int s = 0; s < 8; ++s) {
                const ushort* bp = bt + s * 32 + q * 8;
                short8 b0 = *(const short8*)(bp + c * ROWU);
                short8 b1 = *(const short8*)(bp + (16 + c) * ROWU);
                a0h = __builtin_amdgcn_mfma_f32_16x16x32_bf16(Ah[s], b0, a0h, 0, 0, 0);
                a1h = __builtin_amdgcn_mfma_f32_16x16x32_bf16(Ah[s], b1, a1h, 0, 0, 0);
                a0m = __builtin_amdgcn_mfma_f32_16x16x32_bf16(Am[s], b0, a0m, 0, 0, 0);
                a1m = __builtin_amdgcn_mfma_f32_16x16x32_bf16(Am[s], b1, a1m, 0, 0, 0);
            }
#pragma unroll
            for (int i = 0; i < 4; ++i) {
                float dA = fmaf(-2.f, a0h[i] + a0m[i], wnv0);   // (hi+mid).b_hi rel dist
                top3_insert(packkey(dA, kt * KT + c),      k1[i], k2[i], k3[i]);
                float dB = fmaf(-2.f, a1h[i] + a1m[i], wnv1);
                top3_insert(packkey(dB, kt * KT + 16 + c), k1[i], k2[i], k3[i]);
            }
        }

        if (tid < VT) cnt[tid] = 0;   // cnt untouched in k-loop; barrier below orders
        if (tid == 0) nresc = 0;

        // per-row approx min across the 16 c-lanes (same q) owning the row
        float bmin[4];
#pragma unroll
        for (int i = 0; i < 4; ++i) {
            float md = k1[i];
#pragma unroll
            for (int off = 1; off < 16; off <<= 1)
                md = fminf(md, __shfl_xor(md, off, 64));
            bmin[i] = md;
        }
        __syncthreads();  // (A) cnt/nresc zero visible; all Btile ds_reads done

        // margin filter -> candidate lists. MARGIN=1.25 covers hi-only filter
        // error (sigma<=~0.09, R1-proven at 1.0) + packed-key truncation (<=~0.1).
#pragma unroll
        for (int i = 0; i < 4; ++i) {
            const int row = 16 * w + 4 * q + i;
            const float thr = bmin[i] + 1.25f;
            if (k1[i] <= thr) { union { float f; uint32_t u; } v{k1[i]}; int pos = atomicAdd(&cnt[row], 1); if (pos < CSTR) cand[row * CSTR + pos] = (int)(v.u & 1023u); }
            if (k2[i] <= thr) { union { float f; uint32_t u; } v{k2[i]}; int pos = atomicAdd(&cnt[row], 1); if (pos < CSTR) cand[row * CSTR + pos] = (int)(v.u & 1023u); }
            if (k3[i] <= thr) { union { float f; uint32_t u; } v{k3[i]}; int pos = atomicAdd(&cnt[row], 1); if (pos < CSTR) cand[row * CSTR + pos] = (int)(v.u & 1023u); }
        }
        __syncthreads();  // (B) cand/cnt final

        // compact worklist of rows needing exact rescore (cnt>1, incl. overflow)
        if (tid < VT) slot[tid] = (cnt[tid] > 1) ? atomicAdd(&nresc, 1) : -1;
        __syncthreads();  // (C) slots + nresc known
        const int nr = nresc;

        // fast path: unique candidate IS the argmin
        if (tid < VT && cnt[tid] <= 1) {
            const int bi = cand[tid * CSTR];
            sidx[tid] = bi;
            oidx[((size_t)b * Ll + ly) * Tt + t0 + tid] = (float)bi;
        }

        // rescore batches: Btile is dead -> scratch of RBATCH exact fp32 rows.
        float* Rsc = (float*)Btile;
        for (int base = 0; base < nr; base += RBATCH) {
            // dump: each of the row's 4 owning lanes writes its 64 elems (exact
            // (hi+mid)+lo reconstruction == the fp32 residual, bit-identical)
            {
                const int sl = slot[myrow];
                if (sl >= base && sl < base + RBATCH) {
                    float* dst = Rsc + (size_t)(sl - base) * RSTR + 8 * q;
#pragma unroll
                    for (int s = 0; s < 8; ++s)
#pragma unroll
                        for (int jp = 0; jp < 4; ++jp) {
                            float e0 = (bf2f((ushort)Ah[s][2 * jp]) + bf2f((ushort)Am[s][2 * jp])) + bf2f((ushort)Al[s][2 * jp]);
                            float e1 = (bf2f((ushort)Ah[s][2 * jp + 1]) + bf2f((ushort)Am[s][2 * jp + 1])) + bf2f((ushort)Al[s][2 * jp + 1]);
                            *(float2*)(dst + 32 * s + 2 * jp) = make_float2(e0, e1);
                        }
                }
            }
            __syncthreads();  // dump visible

            // rescore with BIT-EXACT round-1 arithmetic (sequential ascending
            // fmaf dot, groups-of-4 rnorm expression, identical wnorm & dist
            // expr, cc<bi tie-break) so the chosen index replicates the
            // proven-passing kernel.
            if (tid < VT) {
                const int sl = slot[tid];
                if (sl >= base && sl < base + RBATCH) {
                    const int row = tid;
                    const int n = cnt[row];
                    const float* rp = Rsc + (size_t)(sl - base) * RSTR;
                    float rn = 0.f;
                    for (int i2 = 0; i2 < Dd / 4; ++i2) {
                        float r0 = rp[4 * i2], r1 = rp[4 * i2 + 1], r2 = rp[4 * i2 + 2], r3 = rp[4 * i2 + 3];
                        rn += r0 * r0 + r1 * r1 + r2 * r2 + r3 * r3;
                    }
                    const bool ovf = n > CSTR;       // cand list overflowed: exact full scan
                    const int m = ovf ? Kk : n;
                    float bd = __builtin_inff(); int bi = 0x7fffffff;
                    for (int j = 0; j < m; ++j) {
                        const int cc = ovf ? j : cand[row * CSTR + j];
                        const float* wp = cbl + (size_t)cc * Dd;
                        float dot = 0.f;
                        for (int d = 0; d < Dd; ++d)
                            dot = fmaf(rp[d], wp[d], dot);
                        const float dist = (rn - 2.0f * dot) + wnl[cc];
                        if (dist < bd || (dist == bd && cc < bi)) { bd = dist; bi = cc; }
                    }
                    sidx[row] = bi;
                    oidx[((size_t)b * Ll + ly) * Tt + t0 + row] = (float)bi;
                }
            }
            __syncthreads();  // rescore reads done before next batch's dump
        }
        __syncthreads();  // (E) sidx complete (fast path + all batches)

        // residual update: reconstruct exact fp32 (hi+mid)+lo, subtract chosen
        // code (original fp32 codebook), re-split. Exact chain.
        {
            const int cc = sidx[myrow];
            const float* wp = cbl + (size_t)cc * Dd + 8 * q;
#pragma unroll
            for (int s = 0; s < 8; ++s) {
                float4 w0 = *(const float4*)(wp + 32 * s);
                float4 w1 = *(const float4*)(wp + 32 * s + 4);
                float wv[8] = {w0.x, w0.y, w0.z, w0.w, w1.x, w1.y, w1.z, w1.w};
#pragma unroll
                for (int j = 0; j < 8; ++j) {
                    float Rv = (bf2f((ushort)Ah[s][j]) + bf2f((ushort)Am[s][j])) + bf2f((ushort)Al[s][j]);
                    Rv -= wv[j];
                    ushort h_ = f2bf(Rv); float r1 = Rv - bf2f(h_);
                    ushort m_ = f2bf(r1); float r2 = r1 - bf2f(m_);
                    Ah[s][j] = (short)h_; Am[s][j] = (short)m_; Al[s][j] = (short)f2bf(r2);
                }
            }
        }
    }

    // out = x - final residual (exact reconstruct)
    {
        const float* xb = x + (size_t)b * Dd * Tt + t_a;
        float* ob = out + (size_t)b * Dd * Tt + t_a;
#pragma unroll
        for (int s = 0; s < 8; ++s)
#pragma unroll
            for (int j = 0; j < 8; ++j) {
                size_t off = (size_t)(32 * s + 8 * q + j) * Tt;
                float Rv = (bf2f((ushort)Ah[s][j]) + bf2f((ushort)Am[s][j])) + bf2f((ushort)Al[s][j]);
                ob[off] = xb[off] - Rv;
            }
    }
}

// ---------------------------------------------------------------------------
extern "C" void kernel_launch(void* const* d_in, const int* in_sizes, int n_in,
                              void* d_out, int out_size, void* d_ws, size_t ws_size,
                              hipStream_t stream) {
    const float* x  = (const float*)d_in[0];   // (B, D, T)
    const float* cb = (const float*)d_in[1];   // (L, K, D)
    float* out  = (float*)d_out;
    float* oidx = out + (size_t)Bb * Dd * Tt;  // (B, L, T) as fp32 values
    float*  wnbuf = (float*)d_ws;                          // 8192 floats
    ushort* spbuf = (ushort*)((char*)d_ws + 32768);        // hi-split codebook, ~4.46 MB

    prep_kernel<<<Ll * Kk, 64, 0, stream>>>(cb, wnbuf, spbuf);
    rvq_kernel<<<(Bb * Tt) / VT, 256, 0, stream>>>(x, cb, wnbuf, spbuf, out, oidx);
}